// Round 2
// baseline (435.228 us; speedup 1.0000x reference)
//
#include <hip/hip_runtime.h>

#define T_STEPS 1024
#define NB 8192
#define OUT_TSTRIDE (8 * NB)   // floats per time step in out[T,8,B]

__device__ __forceinline__ float sigmoidf_(float x) {
    return 1.0f / (1.0f + __expf(-x));
}

// Core physics for one step: updates (snow, soil), defines all fluxes.
#define CORE(PR, TM, PE)                                                       \
    float snowfall    = ((TM) < Tmin) ? (PR) : 0.0f;                           \
    float rainfall    = (PR) - snowfall;                                       \
    float melt        = fminf(snow, Df * fmaxf((TM) - Tmax, 0.0f));            \
    float evap        = (PE) * fminf(soil * rSmax, 1.0f);                      \
    float baseflow    = Qmax * __expf(nf * fmaxf(Smax - soil, 0.0f));          \
    float surfaceflow = fmaxf(soil - Smax, 0.0f);                              \
    float d_snow      = snowfall - melt;                                       \
    float d_soil = (((rainfall + melt) - evap) - baseflow) - surfaceflow;      \
    snow = fmaxf(snow + d_snow, 1e-6f);                                        \
    soil = fmaxf(soil + d_soil, 1e-6f);

// Warm-up step: state update only, no store.
#define STEP_NS(PR, TM, PE)                                                    \
    do {                                                                       \
        CORE(PR, TM, PE)                                                       \
        (void)rainfall; (void)evap; (void)baseflow; (void)surfaceflow;         \
        (void)d_snow; (void)d_soil;                                            \
    } while (0)

// Main step: store this wave's channel pair (CP compile-time), advance op.
#define STEP_ST(PR, TM, PE)                                                    \
    do {                                                                       \
        CORE(PR, TM, PE)                                                       \
        float sv0, sv1;                                                        \
        if (CP == 0)      { sv0 = snowfall; sv1 = rainfall; }                  \
        else if (CP == 1) { sv0 = melt;     sv1 = evap; }                      \
        else if (CP == 2) { sv0 = baseflow; sv1 = surfaceflow; }               \
        else              { sv0 = d_snow;   sv1 = d_soil; }                    \
        op[0]  = sv0;                                                          \
        op[NB] = sv1;                                                          \
        op += OUT_TSTRIDE;                                                     \
    } while (0)

template <int CP>
__device__ __forceinline__ void run_basin(const float* __restrict__ pp,
                                          const float* __restrict__ tp,
                                          const float* __restrict__ ep,
                                          float* __restrict__ op, float f,
                                          float Smax, float Qmax, float Df,
                                          float Tmax, float Tmin,
                                          int segStart) {
    const float rSmax = 1.0f / Smax;
    const float nf    = -f;
    float snow = 0.0f, soil = 0.0f;

    // Double-buffered register prefetch, depth 32 (two 16-step buffers).
    float Pa[16], Ta[16], Ea[16], Pb[16], Tb[16], Eb[16];

    // ---- warm-up: t in [0, segStart), state only, no stores ----
    if (segStart > 0) {
#pragma unroll
        for (int i = 0; i < 16; ++i) {
            Pa[i] = pp[i * NB]; Ta[i] = tp[i * NB]; Ea[i] = ep[i * NB];
        }
#pragma unroll
        for (int i = 0; i < 16; ++i) {
            Pb[i] = pp[(16 + i) * NB]; Tb[i] = tp[(16 + i) * NB];
            Eb[i] = ep[(16 + i) * NB];
        }
        for (int tb = 0; tb < segStart; tb += 32) {
#pragma unroll
            for (int i = 0; i < 16; ++i) STEP_NS(Pa[i], Ta[i], Ea[i]);
            // refill A with tb+32 .. tb+47 (max segStart+31 <= 799 < 1024)
#pragma unroll
            for (int i = 0; i < 16; ++i) {
                int t2 = tb + 32 + i;
                Pa[i] = pp[t2 * NB]; Ta[i] = tp[t2 * NB]; Ea[i] = ep[t2 * NB];
            }
#pragma unroll
            for (int i = 0; i < 16; ++i) STEP_NS(Pb[i], Tb[i], Eb[i]);
#pragma unroll
            for (int i = 0; i < 16; ++i) {
                int t2 = tb + 48 + i;
                Pb[i] = pp[t2 * NB]; Tb[i] = tp[t2 * NB]; Eb[i] = ep[t2 * NB];
            }
        }
    }

    // ---- main: t in [segStart, segStart+256), store channel pair ----
#pragma unroll
    for (int i = 0; i < 16; ++i) {
        int t = segStart + i;
        Pa[i] = pp[t * NB]; Ta[i] = tp[t * NB]; Ea[i] = ep[t * NB];
    }
#pragma unroll
    for (int i = 0; i < 16; ++i) {
        int t = segStart + 16 + i;
        Pb[i] = pp[t * NB]; Tb[i] = tp[t * NB]; Eb[i] = ep[t * NB];
    }
    for (int tb = segStart; tb < segStart + 256; tb += 32) {
#pragma unroll
        for (int i = 0; i < 16; ++i) STEP_ST(Pa[i], Ta[i], Ea[i]);
        // refill A with tb+32 .. tb+47, clamped to last step (tail re-reads ok)
#pragma unroll
        for (int i = 0; i < 16; ++i) {
            int t2 = tb + 32 + i;
            t2 = (t2 > T_STEPS - 1) ? (T_STEPS - 1) : t2;
            Pa[i] = pp[t2 * NB]; Ta[i] = tp[t2 * NB]; Ea[i] = ep[t2 * NB];
        }
#pragma unroll
        for (int i = 0; i < 16; ++i) STEP_ST(Pb[i], Tb[i], Eb[i]);
#pragma unroll
        for (int i = 0; i < 16; ++i) {
            int t2 = tb + 48 + i;
            t2 = (t2 > T_STEPS - 1) ? (T_STEPS - 1) : t2;
            Pb[i] = pp[t2 * NB]; Tb[i] = tp[t2 * NB]; Eb[i] = ep[t2 * NB];
        }
    }
}

// Grid: 512 blocks = 128 basin-groups x 4 time-segments.
//   XCD co-location: all 4 segment-blocks of a group share blockIdx%8 so their
//   overlapping warm-up streams dedupe in the same per-XCD L2.
// Block: 256 threads = 4 waves; wave w stores channels {2w, 2w+1}.
//   2 blocks/CU -> 8 waves/CU = 2 waves/SIMD.
extern "C" __global__ void __launch_bounds__(256, 2)
    hydro_kernel(const float* __restrict__ prcp, const float* __restrict__ temp,
                 const float* __restrict__ pet, const float* __restrict__ spn,
                 float* __restrict__ out) {
    const int lane  = threadIdx.x & 63;
    const int w     = threadIdx.x >> 6;
    const int b     = blockIdx.x;
    const int x     = b & 7;         // XCD slot
    const int r     = b >> 3;
    const int seg   = r & 3;         // time segment
    const int gg    = r >> 2;
    const int group = gg * 8 + x;    // basin group, co-located per XCD
    const int basin = group * 64 + lane;
    const int segStart = seg << 8;   // seg * 256

    // Denormalize params: sigmoid then affine to bounds.
    const float* p6  = spn + basin * 6;
    const float f    = 0.1f * sigmoidf_(p6[0]);
    const float Smax = 100.0f + 1400.0f * sigmoidf_(p6[1]);
    const float Qmax = 10.0f + 40.0f * sigmoidf_(p6[2]);
    const float Df   = 5.0f * sigmoidf_(p6[3]);
    const float Tmax = 3.0f * sigmoidf_(p6[4]);
    const float Tmin = -3.0f + 3.0f * sigmoidf_(p6[5]);

    const float* pp = prcp + basin;
    const float* tp = temp + basin;
    const float* ep = pet + basin;
    float* op = out + (size_t)segStart * OUT_TSTRIDE + (size_t)(2 * w) * NB + basin;

    // w is wave-uniform -> scalar switch, one specialized loop per wave.
    switch (__builtin_amdgcn_readfirstlane(w)) {
        case 0:  run_basin<0>(pp, tp, ep, op, f, Smax, Qmax, Df, Tmax, Tmin, segStart); break;
        case 1:  run_basin<1>(pp, tp, ep, op, f, Smax, Qmax, Df, Tmax, Tmin, segStart); break;
        case 2:  run_basin<2>(pp, tp, ep, op, f, Smax, Qmax, Df, Tmax, Tmin, segStart); break;
        default: run_basin<3>(pp, tp, ep, op, f, Smax, Qmax, Df, Tmax, Tmin, segStart); break;
    }
}

extern "C" void kernel_launch(void* const* d_in, const int* in_sizes, int n_in,
                              void* d_out, int out_size, void* d_ws,
                              size_t ws_size, hipStream_t stream) {
    const float* prcp = (const float*)d_in[0];
    const float* temp = (const float*)d_in[1];
    const float* pet  = (const float*)d_in[2];
    const float* spn  = (const float*)d_in[3];
    float* out        = (float*)d_out;

    hydro_kernel<<<dim3(512), dim3(256), 0, stream>>>(prcp, temp, pet, spn, out);
}

// Round 3
// 372.521 us; speedup vs baseline: 1.1683x; 1.1683x over previous
//
#include <hip/hip_runtime.h>
#include <stdint.h>

#define NB 8192
#define OUT_TSTRIDE (8 * NB)   // floats per time step in out[T,8,B]
#define TILE 32                // time steps per LDS tile
#define LDS_F 6144             // 3 arrays * 32 rows * 64 basins

__device__ __forceinline__ float sigmoidf_(float x) {
    return 1.0f / (1.0f + __expf(-x));
}

__device__ __forceinline__ void async16(const float* g, float* l) {
    __builtin_amdgcn_global_load_lds(
        (const __attribute__((address_space(1))) void*)g,
        (__attribute__((address_space(3))) void*)l, 16, 0, 0);
}

// Stage 3 arrays x TILE rows x 64 basins into lds (SoA: [arr][row][basin]),
// async, 16B per lane per call, 6 calls per thread (256 threads * 6 * 16B = 24KB).
// LDS dest per wave = wave-uniform base + lane*16 (hardware requirement).
__device__ __forceinline__ void fill_tile(const float* __restrict__ prcp,
                                          const float* __restrict__ temp,
                                          const float* __restrict__ pet,
                                          float* lds, int t0, int tid,
                                          int gbase) {
#pragma unroll
    for (int r = 0; r < 6; ++r) {
        const float* src = (r < 2) ? prcp : ((r < 4) ? temp : pet);
        int tt = ((r & 1) << 4) + (tid >> 4);   // row 0..31 within tile
        int t  = t0 + tt;
        t      = (t > 1023) ? 1023 : t;          // clamp tail prefetch
        const float* g = src + (size_t)t * NB + gbase + ((tid & 15) << 2);
        float* l       = lds + (r << 10) + (tid << 2);
        async16(g, l);
    }
}

// One wave: channel pair CP for 64 basins; compute t in [0, ntiles*32),
// store the pair when tile in [lo1,hi1) or tile >= lo2.
template <int CP>
__device__ void run(const float* __restrict__ prcp,
                    const float* __restrict__ temp,
                    const float* __restrict__ pet, float* __restrict__ out,
                    float (*lds)[LDS_F], int tid, int lane, int gbase,
                    int basin, int ntiles, int lo1, int hi1, int lo2, float f,
                    float Smax, float Qmax, float Df, float Tmax, float Tmin) {
    const float rSmax = 1.0f / Smax;
    const float nf    = -f;
    float snow = 0.0f, soil = 0.0f;
    float* const outBase = out + (size_t)(2 * CP) * NB + basin;

    fill_tile(prcp, temp, pet, lds[0], 0, tid, gbase);
    __syncthreads();   // drains the async fill (implicit vmcnt(0) before barrier)

    for (int tile = 0; tile < ntiles; ++tile) {
        const int cur = tile & 1;
        // async prefetch next tile into the other buffer; drained by the
        // barrier BELOW (after ~2700 cyc of compute -> latency hidden)
        fill_tile(prcp, temp, pet, lds[cur ^ 1], (tile + 1) * TILE, tid, gbase);

        const bool doStore = (tile >= lo1 && tile < hi1) || (tile >= lo2);
        const float* lp    = lds[cur];
        float* o = outBase + (size_t)tile * TILE * OUT_TSTRIDE;
#pragma unroll
        for (int i = 0; i < TILE; ++i) {
            const float P  = lp[i * 64 + lane];          // bank = lane%32: free
            const float Tm = lp[2048 + i * 64 + lane];
            const float Pe = lp[4096 + i * 64 + lane];

            const float snowfall    = (Tm < Tmin) ? P : 0.0f;
            const float rainfall    = P - snowfall;
            const float melt        = fminf(snow, Df * fmaxf(Tm - Tmax, 0.0f));
            const float evap        = Pe * fminf(soil * rSmax, 1.0f);
            const float baseflow    = Qmax * __expf(nf * fmaxf(Smax - soil, 0.0f));
            const float surfaceflow = fmaxf(soil - Smax, 0.0f);
            const float d_snow      = snowfall - melt;
            const float d_soil =
                (((rainfall + melt) - evap) - baseflow) - surfaceflow;
            snow = fmaxf(snow + d_snow, 1e-6f);
            soil = fmaxf(soil + d_soil, 1e-6f);

            if (doStore) {   // wave-uniform -> scalar branch
                float sv0, sv1;
                if (CP == 0)      { sv0 = snowfall; sv1 = rainfall; }
                else if (CP == 1) { sv0 = melt;     sv1 = evap; }
                else if (CP == 2) { sv0 = baseflow; sv1 = surfaceflow; }
                else              { sv0 = d_snow;   sv1 = d_soil; }
                o[(size_t)i * OUT_TSTRIDE]      = sv0;
                o[(size_t)i * OUT_TSTRIDE + NB] = sv1;
            }
        }
        __syncthreads();   // compute done + next fill drained; swap buffers
    }
}

// Grid: 256 blocks = 128 basin-groups x 2 block types, 1 block/CU.
//   type A: waves run t in [0,1024), store their pair in seg0 U seg3
//   type B: waves run t in [0, 768), store their pair in seg1 U seg2
//   A/B of the same group share blockIdx%8 -> same XCD -> L2 dedup of reads.
// Block: 256 threads = 4 waves; wave w = channel pair {2w, 2w+1}.
extern "C" __global__ void __launch_bounds__(256, 1)
    hydro_kernel(const float* __restrict__ prcp, const float* __restrict__ temp,
                 const float* __restrict__ pet, const float* __restrict__ spn,
                 float* __restrict__ out) {
    __shared__ float lds[2][LDS_F];   // 48 KB double buffer

    const int tid   = threadIdx.x;
    const int lane  = tid & 63;
    const int w     = tid >> 6;
    const int b     = blockIdx.x;
    const int group = (b >> 4) * 8 + (b & 7);   // 0..127
    const int type  = (b >> 3) & 1;             // 0=A, 1=B
    const int gbase = group * 64;
    const int basin = gbase + lane;

    const int ntiles = type ? 24 : 32;
    const int lo1    = type ? 8 : 0;
    const int hi1    = type ? 24 : 8;
    const int lo2    = type ? 999 : 24;

    // Denormalize params: sigmoid then affine to bounds.
    const float* p6  = spn + basin * 6;
    const float f    = 0.1f * sigmoidf_(p6[0]);
    const float Smax = 100.0f + 1400.0f * sigmoidf_(p6[1]);
    const float Qmax = 10.0f + 40.0f * sigmoidf_(p6[2]);
    const float Df   = 5.0f * sigmoidf_(p6[3]);
    const float Tmax = 3.0f * sigmoidf_(p6[4]);
    const float Tmin = -3.0f + 3.0f * sigmoidf_(p6[5]);

    switch (__builtin_amdgcn_readfirstlane(w)) {
        case 0:
            run<0>(prcp, temp, pet, out, lds, tid, lane, gbase, basin, ntiles,
                   lo1, hi1, lo2, f, Smax, Qmax, Df, Tmax, Tmin);
            break;
        case 1:
            run<1>(prcp, temp, pet, out, lds, tid, lane, gbase, basin, ntiles,
                   lo1, hi1, lo2, f, Smax, Qmax, Df, Tmax, Tmin);
            break;
        case 2:
            run<2>(prcp, temp, pet, out, lds, tid, lane, gbase, basin, ntiles,
                   lo1, hi1, lo2, f, Smax, Qmax, Df, Tmax, Tmin);
            break;
        default:
            run<3>(prcp, temp, pet, out, lds, tid, lane, gbase, basin, ntiles,
                   lo1, hi1, lo2, f, Smax, Qmax, Df, Tmax, Tmin);
            break;
    }
}

extern "C" void kernel_launch(void* const* d_in, const int* in_sizes, int n_in,
                              void* d_out, int out_size, void* d_ws,
                              size_t ws_size, hipStream_t stream) {
    const float* prcp = (const float*)d_in[0];
    const float* temp = (const float*)d_in[1];
    const float* pet  = (const float*)d_in[2];
    const float* spn  = (const float*)d_in[3];
    float* out        = (float*)d_out;

    hydro_kernel<<<dim3(256), dim3(256), 0, stream>>>(prcp, temp, pet, spn, out);
}

// Round 4
// 368.571 us; speedup vs baseline: 1.1809x; 1.0107x over previous
//
#include <hip/hip_runtime.h>
#include <stdint.h>

#define NB 8192
#define OUT_TSTRIDE (8 * NB)   // floats per time step in out[T,8,B]
#define TILE 32                // time steps per LDS tile
#define LDS_F 6144             // 3 arrays * 32 rows * 64 basins

__device__ __forceinline__ float sigmoidf_(float x) {
    return 1.0f / (1.0f + __expf(-x));
}

__device__ __forceinline__ void async16(const float* g, float* l) {
    __builtin_amdgcn_global_load_lds(
        (const __attribute__((address_space(1))) void*)g,
        (__attribute__((address_space(3))) void*)l, 16, 0, 0);
}

// Stage 3 arrays x TILE rows x 64 basins into lds (SoA: [arr][row][basin]),
// async, 16B per lane per call, 6 calls per thread (256 threads * 6 * 16B = 24KB).
// LDS dest per wave = wave-uniform base + lane*16 (hardware requirement).
__device__ __forceinline__ void fill_tile(const float* __restrict__ prcp,
                                          const float* __restrict__ temp,
                                          const float* __restrict__ pet,
                                          float* lds, int t0, int tid,
                                          int gbase) {
#pragma unroll
    for (int r = 0; r < 6; ++r) {
        const float* src = (r < 2) ? prcp : ((r < 4) ? temp : pet);
        int tt = ((r & 1) << 4) + (tid >> 4);   // row 0..31 within tile
        int t  = t0 + tt;
        t      = (t > 1023) ? 1023 : t;          // clamp tail prefetch
        const float* g = src + (size_t)t * NB + gbase + ((tid & 15) << 2);
        float* l       = lds + (r << 10) + (tid << 2);
        async16(g, l);
    }
}

// One wave: channel pair CP for 64 basins; compute tiles [0, ntiles),
// store the pair when tile in [lo1,hi1) or [lo2,hi2).
template <int CP>
__device__ void run(const float* __restrict__ prcp,
                    const float* __restrict__ temp,
                    const float* __restrict__ pet, float* __restrict__ out,
                    float (*lds)[LDS_F], int tid, int lane, int gbase,
                    int basin, int ntiles, int lo1, int hi1, int lo2, int hi2,
                    float f, float Smax, float Qmax, float Df, float Tmax,
                    float Tmin) {
    const float rSmax = 1.0f / Smax;
    const float nf    = -f;
    float snow = 0.0f, soil = 0.0f;
    float* const outBase = out + (size_t)(2 * CP) * NB + basin;

    fill_tile(prcp, temp, pet, lds[0], 0, tid, gbase);
    __syncthreads();   // drains the async fill (implicit vmcnt(0) before barrier)

    for (int tile = 0; tile < ntiles; ++tile) {
        const int cur = tile & 1;
        // async prefetch next tile into the other buffer; drained by the
        // barrier BELOW (full tile of compute in between -> latency hidden)
        fill_tile(prcp, temp, pet, lds[cur ^ 1], (tile + 1) * TILE, tid, gbase);

        const bool doStore =
            (tile >= lo1 && tile < hi1) || (tile >= lo2 && tile < hi2);
        const float* lp = lds[cur];
        float* o        = outBase + (size_t)tile * TILE * OUT_TSTRIDE;
#pragma unroll
        for (int i = 0; i < TILE; ++i) {
            const float P  = lp[i * 64 + lane];          // bank = lane%32: free
            const float Tm = lp[2048 + i * 64 + lane];
            const float Pe = lp[4096 + i * 64 + lane];

            const float snowfall    = (Tm < Tmin) ? P : 0.0f;
            const float rainfall    = P - snowfall;
            const float melt        = fminf(snow, Df * fmaxf(Tm - Tmax, 0.0f));
            const float evap        = Pe * fminf(soil * rSmax, 1.0f);
            const float baseflow    = Qmax * __expf(nf * fmaxf(Smax - soil, 0.0f));
            const float surfaceflow = fmaxf(soil - Smax, 0.0f);
            const float d_snow      = snowfall - melt;
            const float d_soil =
                (((rainfall + melt) - evap) - baseflow) - surfaceflow;
            snow = fmaxf(snow + d_snow, 1e-6f);
            soil = fmaxf(soil + d_soil, 1e-6f);

            if (doStore) {   // wave-uniform -> scalar branch
                float sv0, sv1;
                if (CP == 0)      { sv0 = snowfall; sv1 = rainfall; }
                else if (CP == 1) { sv0 = melt;     sv1 = evap; }
                else if (CP == 2) { sv0 = baseflow; sv1 = surfaceflow; }
                else              { sv0 = d_snow;   sv1 = d_soil; }
                o[(size_t)i * OUT_TSTRIDE]      = sv0;
                o[(size_t)i * OUT_TSTRIDE + NB] = sv1;
            }
        }
        __syncthreads();   // compute done + next fill drained; swap buffers
    }
}

// Grid: 512 blocks = 128 basin-groups x 4 time-types, 2 blocks/CU.
//   8 segments of 128 steps; type t computes tiles [0, (8-t)*4) and stores
//   segments {t, 7-t}.  Dispatch pairing: blocks b and b+256 share the slot
//   (likely same CU) and carry complementary types {0,3} or {1,2}, so every
//   CU hosts 1664 wave-steps per SIMD -> balanced, with 2-way TLP to hide
//   barrier drains and dependency-chain stalls.
//   All 4 type-blocks of a group share blockIdx%8 -> same XCD -> L2 dedup.
// Block: 256 threads = 4 waves; wave w = channel pair {2w, 2w+1}.
extern "C" __global__ void __launch_bounds__(256, 2)
    hydro_kernel(const float* __restrict__ prcp, const float* __restrict__ temp,
                 const float* __restrict__ pet, const float* __restrict__ spn,
                 float* __restrict__ out) {
    __shared__ float lds[2][LDS_F];   // 48 KB double buffer (2 blocks/CU = 96 KB)

    const int tid  = threadIdx.x;
    const int lane = tid & 63;
    const int w    = tid >> 6;
    const int b    = blockIdx.x;
    const int idx  = b & 255;
    const int pass = b >> 8;                      // 0 or 1
    const int group = (idx >> 4) * 8 + (idx & 7); // 0..127, XCD co-located
    const int t01   = (idx >> 3) & 1;             // 0/1 within pass
    const int type  = pass ? (3 - t01) : t01;     // pass2 complements pass1
    const int gbase = group * 64;
    const int basin = gbase + lane;

    const int ntiles = (8 - type) * 4;
    const int lo1    = type * 4;
    const int hi1    = lo1 + 4;
    const int lo2    = (7 - type) * 4;
    const int hi2    = lo2 + 4;

    // Denormalize params: sigmoid then affine to bounds.
    const float* p6  = spn + basin * 6;
    const float f    = 0.1f * sigmoidf_(p6[0]);
    const float Smax = 100.0f + 1400.0f * sigmoidf_(p6[1]);
    const float Qmax = 10.0f + 40.0f * sigmoidf_(p6[2]);
    const float Df   = 5.0f * sigmoidf_(p6[3]);
    const float Tmax = 3.0f * sigmoidf_(p6[4]);
    const float Tmin = -3.0f + 3.0f * sigmoidf_(p6[5]);

    switch (__builtin_amdgcn_readfirstlane(w)) {
        case 0:
            run<0>(prcp, temp, pet, out, lds, tid, lane, gbase, basin, ntiles,
                   lo1, hi1, lo2, hi2, f, Smax, Qmax, Df, Tmax, Tmin);
            break;
        case 1:
            run<1>(prcp, temp, pet, out, lds, tid, lane, gbase, basin, ntiles,
                   lo1, hi1, lo2, hi2, f, Smax, Qmax, Df, Tmax, Tmin);
            break;
        case 2:
            run<2>(prcp, temp, pet, out, lds, tid, lane, gbase, basin, ntiles,
                   lo1, hi1, lo2, hi2, f, Smax, Qmax, Df, Tmax, Tmin);
            break;
        default:
            run<3>(prcp, temp, pet, out, lds, tid, lane, gbase, basin, ntiles,
                   lo1, hi1, lo2, hi2, f, Smax, Qmax, Df, Tmax, Tmin);
            break;
    }
}

extern "C" void kernel_launch(void* const* d_in, const int* in_sizes, int n_in,
                              void* d_out, int out_size, void* d_ws,
                              size_t ws_size, hipStream_t stream) {
    const float* prcp = (const float*)d_in[0];
    const float* temp = (const float*)d_in[1];
    const float* pet  = (const float*)d_in[2];
    const float* spn  = (const float*)d_in[3];
    float* out        = (float*)d_out;

    hydro_kernel<<<dim3(512), dim3(256), 0, stream>>>(prcp, temp, pet, spn, out);
}